// Round 10
// baseline (1091.281 us; speedup 1.0000x reference)
//
#include <hip/hip_runtime.h>

#define NN   12288
#define FIN  256
#define FOUT 128
#define ALPHA 0.2f
#define NWORDS (NN / 32)   // 384 mask words per row

typedef __attribute__((ext_vector_type(8))) _Float16 half8v;
typedef __attribute__((ext_vector_type(4))) float float4v;
typedef __attribute__((ext_vector_type(4))) int   int4v;

// WhT2 layout: [node>>5][feat 0..127][node&31]  (_Float16)
//   -> one j-tile (32 nodes x 128 feats) is a contiguous 8 KB block.
// maskR layout: [row][j>>5] (uint32), bit b = adj[row][32*(j>>5)+b]

// ---------------------------------------------------------------------------
// Kernel 1: Wh = h @ W (fp32): WhT2 (f16 j-tiled) + Wh1/Wh2 (fp32) +
// per-block max of Wh2 -> mxArr[blockIdx]. One block = 16 nodes, 128 threads.
// ---------------------------------------------------------------------------
__global__ __launch_bounds__(128) void k_wh(
    const float* __restrict__ h,
    const float* __restrict__ W,
    const float* __restrict__ a,
    _Float16* __restrict__ WhT2,
    float* __restrict__ Wh1, float* __restrict__ Wh2,
    float* __restrict__ mxArr)
{
    __shared__ float sP1[2][16], sP2[2][16];
    const int t = threadIdx.x;                     // 0..127
    const int row0 = blockIdx.x * 16;

    float acc[16];
    #pragma unroll
    for (int r = 0; r < 16; ++r) acc[r] = 0.f;

    const float* hb = h + (size_t)row0 * FIN;
    for (int k = 0; k < FIN; k += 4) {
        const float w0 = W[(k + 0) * FOUT + t];
        const float w1 = W[(k + 1) * FOUT + t];
        const float w2 = W[(k + 2) * FOUT + t];
        const float w3 = W[(k + 3) * FOUT + t];
        #pragma unroll
        for (int r = 0; r < 16; ++r) {
            const float4v hv = *(const float4v*)(hb + r * FIN + k);  // uniform
            float s = acc[r];
            s = fmaf(hv.x, w0, s);
            s = fmaf(hv.y, w1, s);
            s = fmaf(hv.z, w2, s);
            s = fmaf(hv.w, w3, s);
            acc[r] = s;
        }
    }

    half8v pk0, pk1;
    #pragma unroll
    for (int r = 0; r < 8; ++r)  pk0[r] = (_Float16)acc[r];
    #pragma unroll
    for (int r = 0; r < 8; ++r)  pk1[r] = (_Float16)acc[8 + r];
    _Float16* dst = WhT2 + (size_t)(row0 >> 5) * 4096 + t * 32 + (row0 & 16);
    *(half8v*)(dst)     = pk0;
    *(half8v*)(dst + 8) = pk1;

    const float a1t = a[t];
    const float a2t = a[FOUT + t];
    const int lane = t & 63, wv = t >> 6;
    #pragma unroll
    for (int r = 0; r < 16; ++r) {
        float v1 = acc[r] * a1t;
        float v2 = acc[r] * a2t;
        #pragma unroll
        for (int off = 1; off < 64; off <<= 1) {
            v1 += __shfl_xor(v1, off, 64);
            v2 += __shfl_xor(v2, off, 64);
        }
        if (lane == 0) { sP1[wv][r] = v1; sP2[wv][r] = v2; }
    }
    __syncthreads();
    if (t < 16) {
        const float v1 = sP1[0][t] + sP1[1][t];
        float v2 = sP2[0][t] + sP2[1][t];
        Wh1[row0 + t] = v1;
        Wh2[row0 + t] = v2;
        #pragma unroll
        for (int off = 1; off < 16; off <<= 1)
            v2 = fmaxf(v2, __shfl_xor(v2, off, 64));
        if (t == 0) mxArr[blockIdx.x] = v2;
    }
}

// ---------------------------------------------------------------------------
// Kernel 1c: pack adj -> row-major bitmask. PURE STREAM, deep ILP:
// each lane owns a private 128 B chunk (8 independent int4 nt-loads in
// flight — R4's pack died on a 1-load ballot chain), packs 32 bits
// in-register (no cross-lane), wave stores 256 B coalesced. HBM-bound.
// wave wid -> row = wid/6, chunk ck = wid%6 (2048 ints each).
// ---------------------------------------------------------------------------
__global__ __launch_bounds__(256) void k_pack(
    const int* __restrict__ adj, unsigned int* __restrict__ maskR)
{
    const int wid  = blockIdx.x * 4 + (threadIdx.x >> 6);
    const int lane = threadIdx.x & 63;
    const int row  = wid / 6;
    const int ck   = wid - row * 6;
    const int4v* src =
        (const int4v*)(adj + (size_t)row * NN + ck * 2048 + lane * 32);
    int4v v[8];
    #pragma unroll
    for (int u = 0; u < 8; ++u)
        v[u] = __builtin_nontemporal_load(src + u);
    unsigned int w = 0;
    #pragma unroll
    for (int u = 0; u < 8; ++u) {
        w |= (v[u].x != 0 ? 1u : 0u) << (u * 4 + 0);
        w |= (v[u].y != 0 ? 1u : 0u) << (u * 4 + 1);
        w |= (v[u].z != 0 ? 1u : 0u) << (u * 4 + 2);
        w |= (v[u].w != 0 ? 1u : 0u) << (u * 4 + 3);
    }
    maskR[(size_t)row * NWORDS + ck * 64 + lane] = w;
}

// ---------------------------------------------------------------------------
// P-fragment from 8 mask bits: leaky -> mask -> exp(e-M); f16 num, f32 sum.
// ---------------------------------------------------------------------------
static __device__ __forceinline__ half8v build_p_bits(
    unsigned int bits, const float* wvv,
    const float wh1, const float M, float& S)
{
    half8v af;
    #pragma unroll
    for (int jj = 0; jj < 8; ++jj) {
        float e = wh1 + wvv[jj];
        e = fmaxf(e, ALPHA * e);
        const float p = ((bits >> jj) & 1u) ? __expf(e - M) : 0.f;
        af[jj] = (_Float16)p;
        S += p;
    }
    return af;
}

static __device__ __forceinline__ half8v build_p(
    const int4v a0, const int4v a1, const float* wvv,
    const float wh1, const float M, float& S)
{
    const int av[8] = {a0.x, a0.y, a0.z, a0.w, a1.x, a1.y, a1.z, a1.w};
    half8v af;
    #pragma unroll
    for (int jj = 0; jj < 8; ++jj) {
        float e = wh1 + wvv[jj];
        e = fmaxf(e, ALPHA * e);
        const float p = av[jj] ? __expf(e - M) : 0.f;
        af[jj] = (_Float16)p;
        S += p;
    }
    return af;
}

// wave-level global max over per-block maxima (single-wave block, no LDS)
static __device__ __forceinline__ float wave_gmax(
    const float* __restrict__ mxArr, int nmx, int lane)
{
    float mv = -1e30f;
    for (int idx = lane; idx < nmx; idx += 64) mv = fmaxf(mv, mxArr[idx]);
    #pragma unroll
    for (int off = 1; off < 64; off <<= 1)
        mv = fmaxf(mv, __shfl_xor(mv, off, 64));
    return mv;
}

// ---------------------------------------------------------------------------
// Kernel 2: fused masked-softmax attention + PV GEMM (partials).
// Grid (NN/32, J); block = ONE wave, no LDS, no barriers. Wave owns 32 rows
// as 2 row-groups of 16; B-fragments loaded once per 32-j tile, reused by
// both row-groups. The 604 MB adj stream is GONE (R10 decoupling: k_pack
// streams it at HBM rate; here a 4 B mask word per row-group per iter —
// 19 MB total, L1-resident lines). Remaining traffic: WhT2 from L2 + pC.
// Mi = leaky(Wh1_i + max_j Wh2_j) >= row max => exp<=1, single pass.
// ---------------------------------------------------------------------------
__global__ __launch_bounds__(64, 2) void k_attn(
    const unsigned int* __restrict__ maskR,
    const _Float16* __restrict__ WhT2,
    const float* __restrict__ Wh1, const float* __restrict__ Wh2,
    const float* __restrict__ mxArr, int nmx,
    float* __restrict__ pC, float* __restrict__ pS)
{
    const int lane = threadIdx.x;
    const int m    = lane & 15;
    const int q    = lane >> 4;
    const int rowbase = blockIdx.x * 32;
    const int J    = gridDim.y;
    const int jy   = blockIdx.y;
    const int jlen = NN / J;
    const int jbeg = jy * jlen;

    const float mxv = wave_gmax(mxArr, nmx, lane);

    float wh1[2], Mi[2];
    const unsigned int* mrow[2];
    #pragma unroll
    for (int rg = 0; rg < 2; ++rg) {
        const int row = rowbase + rg * 16 + m;
        wh1[rg] = Wh1[row];
        const float tm = wh1[rg] + mxv;
        Mi[rg] = fmaxf(tm, ALPHA * tm);
        mrow[rg] = maskR + (size_t)row * NWORDS;
    }

    float4v c[2][8];
    #pragma unroll
    for (int rg = 0; rg < 2; ++rg)
        #pragma unroll
        for (int t = 0; t < 8; ++t) c[rg][t] = (float4v){0.f, 0.f, 0.f, 0.f};
    float S[2] = {0.f, 0.f};

    // prologue: prefetch iter 0's masks + Wh2
    unsigned int nmw0, nmw1;
    float4v nw0, nw1;
    {
        nmw0 = mrow[0][jbeg >> 5];
        nmw1 = mrow[1][jbeg >> 5];
        nw0 = *(const float4v*)(Wh2 + jbeg + q * 8);
        nw1 = *(const float4v*)(Wh2 + jbeg + q * 8 + 4);
    }

    const int iters = jlen / 32;
    for (int it = 0; it < iters; ++it) {
        const int j0 = jbeg + it * 32;

        const unsigned int mw0 = nmw0, mw1 = nmw1;
        const float4v w0 = nw0, w1 = nw1;

        if (it + 1 < iters) {
            const int jn = j0 + 32;
            nmw0 = mrow[0][jn >> 5];
            nmw1 = mrow[1][jn >> 5];
            nw0 = *(const float4v*)(Wh2 + jn + q * 8);
            nw1 = *(const float4v*)(Wh2 + jn + q * 8 + 4);
        }

        // B fragments just-in-time from L2 (8 KB tile, coalesced 1 KB each)
        const _Float16* tp = WhT2 + (size_t)(j0 >> 5) * 4096;
        half8v b[8];
        #pragma unroll
        for (int t = 0; t < 8; ++t)
            b[t] = *(const half8v*)(tp + (t * 16 + m) * 32 + q * 8);

        const float wvv[8] = {w0.x, w0.y, w0.z, w0.w, w1.x, w1.y, w1.z, w1.w};

        const half8v af0 = build_p_bits(mw0 >> (q * 8), wvv, wh1[0], Mi[0], S[0]);
        #pragma unroll
        for (int t = 0; t < 8; ++t)
            c[0][t] = __builtin_amdgcn_mfma_f32_16x16x32_f16(af0, b[t], c[0][t], 0, 0, 0);
        const half8v af1 = build_p_bits(mw1 >> (q * 8), wvv, wh1[1], Mi[1], S[1]);
        #pragma unroll
        for (int t = 0; t < 8; ++t)
            c[1][t] = __builtin_amdgcn_mfma_f32_16x16x32_f16(af1, b[t], c[1][t], 0, 0, 0);
    }

    #pragma unroll
    for (int rg = 0; rg < 2; ++rg) {
        S[rg] += __shfl_xor(S[rg], 16, 64);
        S[rg] += __shfl_xor(S[rg], 32, 64);
        if (q == 0) pS[(size_t)jy * NN + rowbase + rg * 16 + m] = S[rg];
    }

    #pragma unroll
    for (int rg = 0; rg < 2; ++rg)
        #pragma unroll
        for (int t = 0; t < 8; ++t)
            #pragma unroll
            for (int reg = 0; reg < 4; ++reg) {
                const int row = rowbase + rg * 16 + q * 4 + reg;
                pC[((size_t)jy * NN + row) * FOUT + t * 16 + m] = c[rg][t][reg];
            }
}

// ---------------------------------------------------------------------------
// Kernel 3: reduce J partials, normalize, ELU.
// ---------------------------------------------------------------------------
__global__ __launch_bounds__(256) void k_reduce(
    const float* __restrict__ pC, const float* __restrict__ pS,
    float* __restrict__ out, int J)
{
    const int idx = blockIdx.x * 256 + threadIdx.x;  // (row, col/4)
    const int row = idx >> 5;
    const int c4  = (idx & 31) * 4;
    float4v acc = (float4v){0.f, 0.f, 0.f, 0.f};
    float S = 0.f;
    for (int j = 0; j < J; ++j) {
        const float4v v = *(const float4v*)(pC + ((size_t)j * NN + row) * FOUT + c4);
        acc.x += v.x; acc.y += v.y; acc.z += v.z; acc.w += v.w;
        S += pS[(size_t)j * NN + row];
    }
    const float inv = 1.f / fmaxf(S, 1e-30f);
    float4v r;
    #pragma unroll
    for (int k = 0; k < 4; ++k) {
        const float v = acc[k] * inv;
        r[k] = (v > 0.f) ? v : (__expf(v) - 1.f);
    }
    *(float4v*)(out + (size_t)row * FOUT + c4) = r;
}

// ---------------------------------------------------------------------------
// Fallback (tiny ws, no room for masks/partials): direct adj, full j-range.
// ---------------------------------------------------------------------------
__global__ __launch_bounds__(64, 2) void k_attn_fb(
    const int* __restrict__ adj,
    const _Float16* __restrict__ WhT2,
    const float* __restrict__ Wh1, const float* __restrict__ Wh2,
    const float* __restrict__ mxArr, int nmx,
    float* __restrict__ out)
{
    const int lane = threadIdx.x;
    const int m    = lane & 15;
    const int q    = lane >> 4;
    const int rowbase = blockIdx.x * 32;

    const float mxv = wave_gmax(mxArr, nmx, lane);

    float wh1[2], Mi[2];
    const int* rowp[2];
    #pragma unroll
    for (int rg = 0; rg < 2; ++rg) {
        const int row = rowbase + rg * 16 + m;
        wh1[rg] = Wh1[row];
        const float tm = wh1[rg] + mxv;
        Mi[rg] = fmaxf(tm, ALPHA * tm);
        rowp[rg] = adj + (size_t)row * NN;
    }

    float4v c[2][8];
    #pragma unroll
    for (int rg = 0; rg < 2; ++rg)
        #pragma unroll
        for (int t = 0; t < 8; ++t) c[rg][t] = (float4v){0.f, 0.f, 0.f, 0.f};
    float S[2] = {0.f, 0.f};

    for (int j0 = 0; j0 < NN; j0 += 32) {
        const int jb = j0 + q * 8;
        int4v a0[2], a1[2];
        #pragma unroll
        for (int rg = 0; rg < 2; ++rg) {
            a0[rg] = __builtin_nontemporal_load((const int4v*)(rowp[rg] + jb));
            a1[rg] = __builtin_nontemporal_load((const int4v*)(rowp[rg] + jb + 4));
        }
        const _Float16* tp = WhT2 + (size_t)(j0 >> 5) * 4096;
        half8v b[8];
        #pragma unroll
        for (int t = 0; t < 8; ++t)
            b[t] = *(const half8v*)(tp + (t * 16 + m) * 32 + q * 8);
        const float4v w0 = *(const float4v*)(Wh2 + jb);
        const float4v w1 = *(const float4v*)(Wh2 + jb + 4);
        const float wvv[8] = {w0.x, w0.y, w0.z, w0.w, w1.x, w1.y, w1.z, w1.w};
        #pragma unroll
        for (int rg = 0; rg < 2; ++rg) {
            const half8v af = build_p(a0[rg], a1[rg], wvv, wh1[rg], Mi[rg], S[rg]);
            #pragma unroll
            for (int t = 0; t < 8; ++t)
                c[rg][t] = __builtin_amdgcn_mfma_f32_16x16x32_f16(af, b[t], c[rg][t], 0, 0, 0);
        }
    }

    #pragma unroll
    for (int rg = 0; rg < 2; ++rg) {
        S[rg] += __shfl_xor(S[rg], 16, 64);
        S[rg] += __shfl_xor(S[rg], 32, 64);
        #pragma unroll
        for (int reg = 0; reg < 4; ++reg) {
            const int mloc = q * 4 + reg;
            const float Sr = __shfl(S[rg], mloc, 64);
            const float inv = 1.f / fmaxf(Sr, 1e-30f);
            #pragma unroll
            for (int t = 0; t < 8; ++t) {
                const float v = c[rg][t][reg] * inv;
                out[(size_t)(rowbase + rg * 16 + mloc) * FOUT + t * 16 + m] =
                    (v > 0.f) ? v : (__expf(v) - 1.f);
            }
        }
    }
}

// ---------------------------------------------------------------------------
extern "C" void kernel_launch(void* const* d_in, const int* in_sizes, int n_in,
                              void* d_out, int out_size, void* d_ws, size_t ws_size,
                              hipStream_t stream) {
    const float* h   = (const float*)d_in[0];
    const int*   adj = (const int*)d_in[1];
    const float* W   = (const float*)d_in[2];
    const float* a   = (const float*)d_in[3];
    float* out = (float*)d_out;

    char* ws = (char*)d_ws;
    float* Wh1   = (float*)ws;                          // 49152
    float* Wh2   = (float*)(ws + 49152);                // 49152
    float* mxArr = (float*)(ws + 98304);                // 3072
    _Float16* WhT2 = (_Float16*)(ws + 101376);          // 3,145,728
    unsigned int* maskR = (unsigned int*)(ws + 3247104); // 18,874,368
    const size_t base_need = 3247104ULL + 18874368ULL;  // 22,121,472
    const int NB = NN / 16;                             // 768 k_wh blocks

    int J = 8;
    while (J > 1 &&
           base_need + (size_t)J * NN * 4 + (size_t)J * NN * FOUT * 4 > ws_size)
        J >>= 1;
    const bool ok =
        base_need + (size_t)NN * 4 + (size_t)NN * FOUT * 4 <= ws_size;

    k_wh<<<NB, 128, 0, stream>>>(h, W, a, WhT2, Wh1, Wh2, mxArr);
    if (ok) {
        float* pS = (float*)(ws + base_need);
        float* pC = pS + (size_t)J * NN;
        k_pack<<<(NN * 6) / 4, 256, 0, stream>>>(adj, maskR);
        k_attn<<<dim3(NN / 32, J), 64, 0, stream>>>(maskR, WhT2, Wh1, Wh2,
                                                    mxArr, NB, pC, pS);
        k_reduce<<<(NN * (FOUT / 4)) / 256, 256, 0, stream>>>(pC, pS, out, J);
    } else {
        k_attn_fb<<<NN / 32, 64, 0, stream>>>(adj, WhT2, Wh1, Wh2, mxArr, NB, out);
    }
}

// Round 11
// 994.522 us; speedup vs baseline: 1.0973x; 1.0973x over previous
//
#include <hip/hip_runtime.h>

#define NN   12288
#define FIN  256
#define FOUT 128
#define ALPHA 0.2f
#define NWORDS (NN / 32)   // 384 mask words per row

typedef __attribute__((ext_vector_type(8))) _Float16 half8v;
typedef __attribute__((ext_vector_type(4))) float float4v;
typedef __attribute__((ext_vector_type(4))) int   int4v;

// WhT2 layout: [node>>5][feat 0..127][node&31]  (_Float16)
//   -> one j-tile (32 nodes x 128 feats) is a contiguous 8 KB block.
// maskR layout: [row][j>>5] (uint32), bit b = adj[row][32*(j>>5)+b]

// ---------------------------------------------------------------------------
// Kernel 1: Wh = h @ W (fp32): WhT2 (f16 j-tiled) + Wh1/Wh2 (fp32) +
// per-block max of Wh2 -> mxArr[blockIdx]. One block = 16 nodes, 128 threads.
// ---------------------------------------------------------------------------
__global__ __launch_bounds__(128) void k_wh(
    const float* __restrict__ h,
    const float* __restrict__ W,
    const float* __restrict__ a,
    _Float16* __restrict__ WhT2,
    float* __restrict__ Wh1, float* __restrict__ Wh2,
    float* __restrict__ mxArr)
{
    __shared__ float sP1[2][16], sP2[2][16];
    const int t = threadIdx.x;                     // 0..127
    const int row0 = blockIdx.x * 16;

    float acc[16];
    #pragma unroll
    for (int r = 0; r < 16; ++r) acc[r] = 0.f;

    const float* hb = h + (size_t)row0 * FIN;
    for (int k = 0; k < FIN; k += 4) {
        const float w0 = W[(k + 0) * FOUT + t];
        const float w1 = W[(k + 1) * FOUT + t];
        const float w2 = W[(k + 2) * FOUT + t];
        const float w3 = W[(k + 3) * FOUT + t];
        #pragma unroll
        for (int r = 0; r < 16; ++r) {
            const float4v hv = *(const float4v*)(hb + r * FIN + k);  // uniform
            float s = acc[r];
            s = fmaf(hv.x, w0, s);
            s = fmaf(hv.y, w1, s);
            s = fmaf(hv.z, w2, s);
            s = fmaf(hv.w, w3, s);
            acc[r] = s;
        }
    }

    half8v pk0, pk1;
    #pragma unroll
    for (int r = 0; r < 8; ++r)  pk0[r] = (_Float16)acc[r];
    #pragma unroll
    for (int r = 0; r < 8; ++r)  pk1[r] = (_Float16)acc[8 + r];
    _Float16* dst = WhT2 + (size_t)(row0 >> 5) * 4096 + t * 32 + (row0 & 16);
    *(half8v*)(dst)     = pk0;
    *(half8v*)(dst + 8) = pk1;

    const float a1t = a[t];
    const float a2t = a[FOUT + t];
    const int lane = t & 63, wv = t >> 6;
    #pragma unroll
    for (int r = 0; r < 16; ++r) {
        float v1 = acc[r] * a1t;
        float v2 = acc[r] * a2t;
        #pragma unroll
        for (int off = 1; off < 64; off <<= 1) {
            v1 += __shfl_xor(v1, off, 64);
            v2 += __shfl_xor(v2, off, 64);
        }
        if (lane == 0) { sP1[wv][r] = v1; sP2[wv][r] = v2; }
    }
    __syncthreads();
    if (t < 16) {
        const float v1 = sP1[0][t] + sP1[1][t];
        float v2 = sP2[0][t] + sP2[1][t];
        Wh1[row0 + t] = v1;
        Wh2[row0 + t] = v2;
        #pragma unroll
        for (int off = 1; off < 16; off <<= 1)
            v2 = fmaxf(v2, __shfl_xor(v2, off, 64));
        if (t == 0) mxArr[blockIdx.x] = v2;
    }
}

// ---------------------------------------------------------------------------
// Kernel 1c: pack adj -> row-major bitmask, v3.
// R4 lesson: needs >=8 loads in flight. R10 lesson: lane-private 128B chunks
// make 128B-stride half-line accesses (nt refetch -> ~2.4GB traffic).
// v3: identity lane->column mapping. Per step the wave issues 8 INDEPENDENT
// fully-coalesced 256B loads (whole cache lines, no nt), 8 ballots (SALU),
// one 64B coalesced mask-line store. One wave per row, 24 steps.
// ---------------------------------------------------------------------------
__global__ __launch_bounds__(256) void k_pack(
    const int* __restrict__ adj, unsigned int* __restrict__ maskR)
{
    const int row  = blockIdx.x * 4 + (threadIdx.x >> 6);
    const int lane = threadIdx.x & 63;
    const int* rp = adj + (size_t)row * NN;
    unsigned int* mrow = maskR + (size_t)row * NWORDS;

    for (int step = 0; step < NN / 512; ++step) {
        const int base = step * 512;
        int v[8];
        #pragma unroll
        for (int g = 0; g < 8; ++g)
            v[g] = rp[base + g * 64 + lane];
        unsigned long long b[8];
        #pragma unroll
        for (int g = 0; g < 8; ++g)
            b[g] = __ballot(v[g] != 0);
        // bit i of b[g] = column base + g*64 + i  ->  word step*16 + 2g + h
        unsigned int w = 0;
        #pragma unroll
        for (int g = 0; g < 8; ++g) {
            const unsigned int lo = (unsigned int)b[g];
            const unsigned int hi = (unsigned int)(b[g] >> 32);
            w = (lane == 2 * g)     ? lo : w;
            w = (lane == 2 * g + 1) ? hi : w;
        }
        if (lane < 16) mrow[step * 16 + lane] = w;
    }
}

// ---------------------------------------------------------------------------
// P-fragment from 8 mask bits: leaky -> mask -> exp(e-M); f16 num, f32 sum.
// ---------------------------------------------------------------------------
static __device__ __forceinline__ half8v build_p_bits(
    unsigned int bits, const float* wvv,
    const float wh1, const float M, float& S)
{
    half8v af;
    #pragma unroll
    for (int jj = 0; jj < 8; ++jj) {
        float e = wh1 + wvv[jj];
        e = fmaxf(e, ALPHA * e);
        const float p = ((bits >> jj) & 1u) ? __expf(e - M) : 0.f;
        af[jj] = (_Float16)p;
        S += p;
    }
    return af;
}

static __device__ __forceinline__ half8v build_p(
    const int4v a0, const int4v a1, const float* wvv,
    const float wh1, const float M, float& S)
{
    const int av[8] = {a0.x, a0.y, a0.z, a0.w, a1.x, a1.y, a1.z, a1.w};
    half8v af;
    #pragma unroll
    for (int jj = 0; jj < 8; ++jj) {
        float e = wh1 + wvv[jj];
        e = fmaxf(e, ALPHA * e);
        const float p = av[jj] ? __expf(e - M) : 0.f;
        af[jj] = (_Float16)p;
        S += p;
    }
    return af;
}

// wave-level global max over per-block maxima (single-wave block, no LDS)
static __device__ __forceinline__ float wave_gmax(
    const float* __restrict__ mxArr, int nmx, int lane)
{
    float mv = -1e30f;
    for (int idx = lane; idx < nmx; idx += 64) mv = fmaxf(mv, mxArr[idx]);
    #pragma unroll
    for (int off = 1; off < 64; off <<= 1)
        mv = fmaxf(mv, __shfl_xor(mv, off, 64));
    return mv;
}

// ---------------------------------------------------------------------------
// Kernel 2: fused masked-softmax attention + PV GEMM (partials).
// Grid (NN/32, J); block = ONE wave, no LDS, no barriers. Wave owns 32 rows
// as 2 row-groups of 16; B-fragments loaded once per 32-j tile, reused by
// both row-groups. adj stream handled by k_pack; here 4 B mask word per
// row-group per iter (19 MB total, L1-resident lines). Measured-consistent
// at ~83us in R10. Mi = leaky(Wh1_i + max_j Wh2_j) >= row max => exp<=1.
// ---------------------------------------------------------------------------
__global__ __launch_bounds__(64, 2) void k_attn(
    const unsigned int* __restrict__ maskR,
    const _Float16* __restrict__ WhT2,
    const float* __restrict__ Wh1, const float* __restrict__ Wh2,
    const float* __restrict__ mxArr, int nmx,
    float* __restrict__ pC, float* __restrict__ pS)
{
    const int lane = threadIdx.x;
    const int m    = lane & 15;
    const int q    = lane >> 4;
    const int rowbase = blockIdx.x * 32;
    const int J    = gridDim.y;
    const int jy   = blockIdx.y;
    const int jlen = NN / J;
    const int jbeg = jy * jlen;

    const float mxv = wave_gmax(mxArr, nmx, lane);

    float wh1[2], Mi[2];
    const unsigned int* mrow[2];
    #pragma unroll
    for (int rg = 0; rg < 2; ++rg) {
        const int row = rowbase + rg * 16 + m;
        wh1[rg] = Wh1[row];
        const float tm = wh1[rg] + mxv;
        Mi[rg] = fmaxf(tm, ALPHA * tm);
        mrow[rg] = maskR + (size_t)row * NWORDS;
    }

    float4v c[2][8];
    #pragma unroll
    for (int rg = 0; rg < 2; ++rg)
        #pragma unroll
        for (int t = 0; t < 8; ++t) c[rg][t] = (float4v){0.f, 0.f, 0.f, 0.f};
    float S[2] = {0.f, 0.f};

    // prologue: prefetch iter 0's masks + Wh2
    unsigned int nmw0, nmw1;
    float4v nw0, nw1;
    {
        nmw0 = mrow[0][jbeg >> 5];
        nmw1 = mrow[1][jbeg >> 5];
        nw0 = *(const float4v*)(Wh2 + jbeg + q * 8);
        nw1 = *(const float4v*)(Wh2 + jbeg + q * 8 + 4);
    }

    const int iters = jlen / 32;
    for (int it = 0; it < iters; ++it) {
        const int j0 = jbeg + it * 32;

        const unsigned int mw0 = nmw0, mw1 = nmw1;
        const float4v w0 = nw0, w1 = nw1;

        if (it + 1 < iters) {
            const int jn = j0 + 32;
            nmw0 = mrow[0][jn >> 5];
            nmw1 = mrow[1][jn >> 5];
            nw0 = *(const float4v*)(Wh2 + jn + q * 8);
            nw1 = *(const float4v*)(Wh2 + jn + q * 8 + 4);
        }

        // B fragments just-in-time from L2 (8 KB tile, coalesced 1 KB each)
        const _Float16* tp = WhT2 + (size_t)(j0 >> 5) * 4096;
        half8v b[8];
        #pragma unroll
        for (int t = 0; t < 8; ++t)
            b[t] = *(const half8v*)(tp + (t * 16 + m) * 32 + q * 8);

        const float wvv[8] = {w0.x, w0.y, w0.z, w0.w, w1.x, w1.y, w1.z, w1.w};

        const half8v af0 = build_p_bits(mw0 >> (q * 8), wvv, wh1[0], Mi[0], S[0]);
        #pragma unroll
        for (int t = 0; t < 8; ++t)
            c[0][t] = __builtin_amdgcn_mfma_f32_16x16x32_f16(af0, b[t], c[0][t], 0, 0, 0);
        const half8v af1 = build_p_bits(mw1 >> (q * 8), wvv, wh1[1], Mi[1], S[1]);
        #pragma unroll
        for (int t = 0; t < 8; ++t)
            c[1][t] = __builtin_amdgcn_mfma_f32_16x16x32_f16(af1, b[t], c[1][t], 0, 0, 0);
    }

    #pragma unroll
    for (int rg = 0; rg < 2; ++rg) {
        S[rg] += __shfl_xor(S[rg], 16, 64);
        S[rg] += __shfl_xor(S[rg], 32, 64);
        if (q == 0) pS[(size_t)jy * NN + rowbase + rg * 16 + m] = S[rg];
    }

    #pragma unroll
    for (int rg = 0; rg < 2; ++rg)
        #pragma unroll
        for (int t = 0; t < 8; ++t)
            #pragma unroll
            for (int reg = 0; reg < 4; ++reg) {
                const int row = rowbase + rg * 16 + q * 4 + reg;
                pC[((size_t)jy * NN + row) * FOUT + t * 16 + m] = c[rg][t][reg];
            }
}

// ---------------------------------------------------------------------------
// Kernel 3: reduce J partials, normalize, ELU.
// ---------------------------------------------------------------------------
__global__ __launch_bounds__(256) void k_reduce(
    const float* __restrict__ pC, const float* __restrict__ pS,
    float* __restrict__ out, int J)
{
    const int idx = blockIdx.x * 256 + threadIdx.x;  // (row, col/4)
    const int row = idx >> 5;
    const int c4  = (idx & 31) * 4;
    float4v acc = (float4v){0.f, 0.f, 0.f, 0.f};
    float S = 0.f;
    for (int j = 0; j < J; ++j) {
        const float4v v = *(const float4v*)(pC + ((size_t)j * NN + row) * FOUT + c4);
        acc.x += v.x; acc.y += v.y; acc.z += v.z; acc.w += v.w;
        S += pS[(size_t)j * NN + row];
    }
    const float inv = 1.f / fmaxf(S, 1e-30f);
    float4v r;
    #pragma unroll
    for (int k = 0; k < 4; ++k) {
        const float v = acc[k] * inv;
        r[k] = (v > 0.f) ? v : (__expf(v) - 1.f);
    }
    *(float4v*)(out + (size_t)row * FOUT + c4) = r;
}

// ---------------------------------------------------------------------------
// Fallback (tiny ws, no room for masks/partials): direct adj, full j-range.
// ---------------------------------------------------------------------------
__global__ __launch_bounds__(64, 2) void k_attn_fb(
    const int* __restrict__ adj,
    const _Float16* __restrict__ WhT2,
    const float* __restrict__ Wh1, const float* __restrict__ Wh2,
    const float* __restrict__ mxArr, int nmx,
    float* __restrict__ out)
{
    const int lane = threadIdx.x;
    const int m    = lane & 15;
    const int q    = lane >> 4;
    const int rowbase = blockIdx.x * 32;

    const float mxv = wave_gmax(mxArr, nmx, lane);

    float wh1[2], Mi[2];
    const int* rowp[2];
    #pragma unroll
    for (int rg = 0; rg < 2; ++rg) {
        const int row = rowbase + rg * 16 + m;
        wh1[rg] = Wh1[row];
        const float tm = wh1[rg] + mxv;
        Mi[rg] = fmaxf(tm, ALPHA * tm);
        rowp[rg] = adj + (size_t)row * NN;
    }

    float4v c[2][8];
    #pragma unroll
    for (int rg = 0; rg < 2; ++rg)
        #pragma unroll
        for (int t = 0; t < 8; ++t) c[rg][t] = (float4v){0.f, 0.f, 0.f, 0.f};
    float S[2] = {0.f, 0.f};

    for (int j0 = 0; j0 < NN; j0 += 32) {
        const int jb = j0 + q * 8;
        int4v a0[2], a1[2];
        #pragma unroll
        for (int rg = 0; rg < 2; ++rg) {
            a0[rg] = *(const int4v*)(rowp[rg] + jb);
            a1[rg] = *(const int4v*)(rowp[rg] + jb + 4);
        }
        const _Float16* tp = WhT2 + (size_t)(j0 >> 5) * 4096;
        half8v b[8];
        #pragma unroll
        for (int t = 0; t < 8; ++t)
            b[t] = *(const half8v*)(tp + (t * 16 + m) * 32 + q * 8);
        const float4v w0 = *(const float4v*)(Wh2 + jb);
        const float4v w1 = *(const float4v*)(Wh2 + jb + 4);
        const float wvv[8] = {w0.x, w0.y, w0.z, w0.w, w1.x, w1.y, w1.z, w1.w};
        #pragma unroll
        for (int rg = 0; rg < 2; ++rg) {
            const half8v af = build_p(a0[rg], a1[rg], wvv, wh1[rg], Mi[rg], S[rg]);
            #pragma unroll
            for (int t = 0; t < 8; ++t)
                c[rg][t] = __builtin_amdgcn_mfma_f32_16x16x32_f16(af, b[t], c[rg][t], 0, 0, 0);
        }
    }

    #pragma unroll
    for (int rg = 0; rg < 2; ++rg) {
        S[rg] += __shfl_xor(S[rg], 16, 64);
        S[rg] += __shfl_xor(S[rg], 32, 64);
        #pragma unroll
        for (int reg = 0; reg < 4; ++reg) {
            const int mloc = q * 4 + reg;
            const float Sr = __shfl(S[rg], mloc, 64);
            const float inv = 1.f / fmaxf(Sr, 1e-30f);
            #pragma unroll
            for (int t = 0; t < 8; ++t) {
                const float v = c[rg][t][reg] * inv;
                out[(size_t)(rowbase + rg * 16 + mloc) * FOUT + t * 16 + m] =
                    (v > 0.f) ? v : (__expf(v) - 1.f);
            }
        }
    }
}

// ---------------------------------------------------------------------------
extern "C" void kernel_launch(void* const* d_in, const int* in_sizes, int n_in,
                              void* d_out, int out_size, void* d_ws, size_t ws_size,
                              hipStream_t stream) {
    const float* h   = (const float*)d_in[0];
    const int*   adj = (const int*)d_in[1];
    const float* W   = (const float*)d_in[2];
    const float* a   = (const float*)d_in[3];
    float* out = (float*)d_out;

    char* ws = (char*)d_ws;
    float* Wh1   = (float*)ws;                          // 49152
    float* Wh2   = (float*)(ws + 49152);                // 49152
    float* mxArr = (float*)(ws + 98304);                // 3072
    _Float16* WhT2 = (_Float16*)(ws + 101376);          // 3,145,728
    unsigned int* maskR = (unsigned int*)(ws + 3247104); // 18,874,368
    const size_t base_need = 3247104ULL + 18874368ULL;  // 22,121,472
    const int NB = NN / 16;                             // 768 k_wh blocks

    int J = 8;
    while (J > 1 &&
           base_need + (size_t)J * NN * 4 + (size_t)J * NN * FOUT * 4 > ws_size)
        J >>= 1;
    const bool ok =
        base_need + (size_t)NN * 4 + (size_t)NN * FOUT * 4 <= ws_size;

    k_wh<<<NB, 128, 0, stream>>>(h, W, a, WhT2, Wh1, Wh2, mxArr);
    if (ok) {
        float* pS = (float*)(ws + base_need);
        float* pC = pS + (size_t)J * NN;
        k_pack<<<NN / 4, 256, 0, stream>>>(adj, maskR);
        k_attn<<<dim3(NN / 32, J), 64, 0, stream>>>(maskR, WhT2, Wh1, Wh2,
                                                    mxArr, NB, pC, pS);
        k_reduce<<<(NN * (FOUT / 4)) / 256, 256, 0, stream>>>(pC, pS, out, J);
    } else {
        k_attn_fb<<<NN / 32, 64, 0, stream>>>(adj, WhT2, Wh1, Wh2, mxArr, NB, out);
    }
}